// Round 3
// baseline (1485.321 us; speedup 1.0000x reference)
//
#include <hip/hip_runtime.h>

#define DEG 17
#define NSTEPS 32
#define HD 96
#define NODES 1024
#define NBLK 512        // 2 nodes per block
#define Z1STR 40
#define Z2STR 44

// ws float offsets
#define WS_H      0
#define WS_S      98304
#define WS_U0     196608
#define WS_U1     393216
#define WS_XIN    590352
#define WS_GX     688656
#define WS_W1P    1081872
#define WS_W2P    1094160
#define WS_LOSSP  1106448          // 32*512 floats
#define WS_CNTP   (WS_LOSSP+16384) // 32*512 ints

// ---------------- init0: pad W1/W2 to [96][128] (8-wide groups of 6 cols)
__global__ void wpad_kernel(const float* __restrict__ msg_Ws,
                            float* __restrict__ W1p, float* __restrict__ W2p)
{
  const int k = blockIdx.x;        // 0..95
  const int tid = threadIdx.x;     // 0..127
  const int jg = tid >> 3, jj = tid & 7;
  float v1 = 0.f, v2 = 0.f;
  if (jj < 6) {
    v1 = msg_Ws[k*96 + jg*6 + jj];
    v2 = msg_Ws[9216 + k*96 + jg*6 + jj];
  }
  W1p[k*128 + tid] = v1;
  W2p[k*128 + tid] = v2;
}

// ---------------- init1: embedding + input MLP -> xin (one-time)
__global__ void init_kernel(
    const int* __restrict__ x,
    const float* __restrict__ digit_emb,
    const float* __restrict__ row_emb,
    const float* __restrict__ col_emb,
    const float* __restrict__ in0_W,
    const float* __restrict__ in0_b,
    const float* __restrict__ in_Ws,
    const float* __restrict__ in_bs,
    float* __restrict__ xin)
{
  const int node = blockIdx.x;
  const int j = threadIdx.x;
  const int n = node & 63;
  const int r = n >> 3, c = n & 7;
  __shared__ float feat[48];
  __shared__ float za[HD];
  __shared__ float zb[HD];
  if (j < 16)      feat[j] = digit_emb[x[node]*16 + j];
  else if (j < 32) feat[j] = row_emb[r*16 + (j-16)];
  else if (j < 48) feat[j] = col_emb[c*16 + (j-32)];
  __syncthreads();
  float a = in0_b[j];
  for (int k = 0; k < 48; ++k) a = fmaf(feat[k], in0_W[k*HD + j], a);
  za[j] = fmaxf(a, 0.f);
  __syncthreads();
  a = in_bs[j];
  for (int k = 0; k < HD; ++k) a = fmaf(za[k], in_Ws[k*HD + j], a);
  zb[j] = fmaxf(a, 0.f);
  __syncthreads();
  a = in_bs[HD + j];
  for (int k = 0; k < HD; ++k) a = fmaf(zb[k], in_Ws[9216 + k*HD + j], a);
  za[j] = fmaxf(a, 0.f);
  __syncthreads();
  a = in_bs[2*HD + j];
  for (int k = 0; k < HD; ++k) a = fmaf(za[k], in_Ws[2*9216 + k*HD + j], a);
  xin[node*HD + j] = a;
}

// ---------------- init2: gx = xin @ W_ih[96:192] + b_ih + b_hh (one-time)
__global__ __launch_bounds__(384) void gx_kernel(
    const float* __restrict__ xin, const float* __restrict__ W_ih,
    const float* __restrict__ b_ih, const float* __restrict__ b_hh,
    float* __restrict__ gx)
{
  __shared__ float xs[4*HD];
  const int tid = threadIdx.x;
  const int base = blockIdx.x * 4;
  {
    const int m = tid / HD, k = tid - m*HD;
    xs[m*HD + k] = xin[(base+m)*HD + k];
  }
  __syncthreads();
  const int j = tid;
  float a0 = b_ih[j] + b_hh[j], a1 = a0, a2 = a0, a3 = a0;
  for (int k = 0; k < HD; ++k) {
    const float w = W_ih[(96+k)*384 + j];
    a0 = fmaf(xs[k], w, a0);
    a1 = fmaf(xs[HD+k], w, a1);
    a2 = fmaf(xs[2*HD+k], w, a2);
    a3 = fmaf(xs[3*HD+k], w, a3);
  }
  gx[(base+0)*384 + j] = a0;
  gx[(base+1)*384 + j] = a1;
  gx[(base+2)*384 + j] = a2;
  gx[(base+3)*384 + j] = a3;
}

// ---------------- one recurrent step (2 nodes / block, 512 blocks) ----------
__global__ __launch_bounds__(384, 3) void step_kernel(
    const float* __restrict__ u_prev, float* __restrict__ u_next,
    float* __restrict__ h, float* __restrict__ s,
    const float* __restrict__ gx,
    const int* __restrict__ edges,
    const float* __restrict__ W1p, const float* __restrict__ W2p,
    const float* __restrict__ msg0_W, const float* __restrict__ msg0_b,
    const float* __restrict__ msg_Ws, const float* __restrict__ msg_bs,
    const float* __restrict__ W_ih, const float* __restrict__ W_hh,
    const float* __restrict__ pred_W, const float* __restrict__ pred_b,
    const int* __restrict__ target,
    float* __restrict__ lossP, int* __restrict__ cntP,
    float* __restrict__ final_pred_out, int step)
{
  __shared__ float sm[8064];             // 31.5 KB -> 2 blocks/CU
  float* const z1s = sm;                 // [96][40]
  float* const z2s = sm + 3840;          // [96][44]
  // overlays of z1s region (dead after GEMM1):
  float* const s3t   = sm;               // [96][2]
  float* const msgh  = sm + 192;         // [192][2]
  float* const h2t   = sm + 576;         // [96][2]
  float* const lgt   = sm + 768;         // 32
  float* const gates = sm + 800;         // [2][384]
  float* const P2    = sm + 1568;        // [96][20]
  // overlays of z2s region (dead after GEMM2):
  float* const P3 = z2s;                 // [16][2][96]
  float* const PL = z2s;                 // [4][2][384]
  float* const PU = z2s;                 // [8][2][192]

  const int tid = threadIdx.x;
  const int blk = blockIdx.x;
  const int base = blk * 2;              // first node
  const int bb = blk >> 5;               // batch sample
  const int nbase = (blk & 31) * 2;      // node-in-sample of m=0

  // ===== phase 1: z1 rows (rows = m*20+r; pads r=17..19 zero) =====
  if (tid < 320) {
    const int row = tid % 40;
    const int kq  = tid / 40;            // 0..7, 12 k each
    const int k0 = kq*12;
    const int m = row / 20, r = row - m*20;
    if (r < 17) {
      const int nbr = edges[(nbase + m)*DEG + r];
      const float* upe = u_prev + (bb*64 + nbr)*192 + k0;
      const float* ups = u_prev + (base+m)*192 + 96 + k0;
      const float* b0p = msg0_b + k0;
      #pragma unroll
      for (int t = 0; t < 3; ++t) {
        const float4 ue = *(const float4*)(upe + t*4);
        const float4 us = *(const float4*)(ups + t*4);
        const float4 b0 = *(const float4*)(b0p + t*4);
        z1s[(k0+t*4+0)*Z1STR + row] = fmaxf(ue.x+us.x+b0.x, 0.f);
        z1s[(k0+t*4+1)*Z1STR + row] = fmaxf(ue.y+us.y+b0.y, 0.f);
        z1s[(k0+t*4+2)*Z1STR + row] = fmaxf(ue.z+us.z+b0.z, 0.f);
        z1s[(k0+t*4+3)*Z1STR + row] = fmaxf(ue.w+us.w+b0.w, 0.f);
      }
    } else {
      #pragma unroll
      for (int t = 0; t < 12; ++t) z1s[(k0+t)*Z1STR + row] = 0.f;
    }
  }
  __syncthreads();

  // ===== phase 2: GEMM1  z2 = relu(z1 @ W1 + b1)  (40x96 @ 96x96) =====
  if (tid < 320) {
    const int jg = tid & 15, dg = tid >> 4;   // 16 x 20
    const int j6 = jg*6, j8 = jg*8, d2 = dg*2;
    float acc[2][6];
    #pragma unroll
    for (int dd = 0; dd < 2; ++dd)
      #pragma unroll
      for (int jj = 0; jj < 6; ++jj) acc[dd][jj] = 0.f;
    #pragma unroll 4
    for (int k = 0; k < HD; ++k) {
      const float2 z = *(const float2*)&z1s[k*Z1STR + d2];
      const float* wp = W1p + k*128 + j8;
      const float4 wa = *(const float4*)wp;
      const float2 wb = *(const float2*)(wp + 4);
      const float we[6] = {wa.x, wa.y, wa.z, wa.w, wb.x, wb.y};
      #pragma unroll
      for (int jj = 0; jj < 6; ++jj) {
        acc[0][jj] = fmaf(z.x, we[jj], acc[0][jj]);
        acc[1][jj] = fmaf(z.y, we[jj], acc[1][jj]);
      }
    }
    #pragma unroll
    for (int jj = 0; jj < 6; ++jj) {
      const float b1 = msg_bs[j6 + jj];
      float2 q;
      q.x = fmaxf(acc[0][jj] + b1, 0.f);
      q.y = fmaxf(acc[1][jj] + b1, 0.f);
      *(float2*)&z2s[(j6+jj)*Z2STR + d2] = q;
    }
  }
  __syncthreads();

  // ===== phase 3: GEMM2 + relu + masked 2-row partial sums; stage h =====
  if (tid < 320) {
    const int jg = tid & 15, dg = tid >> 4;
    const int j6 = jg*6, j8 = jg*8, d2 = dg*2;
    const int rl = (dg % 10) * 2;
    float acc[2][6];
    #pragma unroll
    for (int dd = 0; dd < 2; ++dd)
      #pragma unroll
      for (int jj = 0; jj < 6; ++jj) acc[dd][jj] = 0.f;
    #pragma unroll 4
    for (int k = 0; k < HD; ++k) {
      const float2 z = *(const float2*)&z2s[k*Z2STR + d2];
      const float* wp = W2p + k*128 + j8;
      const float4 wa = *(const float4*)wp;
      const float2 wb = *(const float2*)(wp + 4);
      const float we[6] = {wa.x, wa.y, wa.z, wa.w, wb.x, wb.y};
      #pragma unroll
      for (int jj = 0; jj < 6; ++jj) {
        acc[0][jj] = fmaf(z.x, we[jj], acc[0][jj]);
        acc[1][jj] = fmaf(z.y, we[jj], acc[1][jj]);
      }
    }
    const bool v0 = (rl <= 16), v1 = (rl < 16);
    #pragma unroll
    for (int jj = 0; jj < 6; ++jj) {
      const float b2 = msg_bs[96 + j6 + jj];
      float p = 0.f;
      if (v0) p += fmaxf(acc[0][jj] + b2, 0.f);
      if (v1) p += fmaxf(acc[1][jj] + b2, 0.f);
      P2[(j6+jj)*20 + dg] = p;
    }
  } else {
    const int idx = tid - 320;             // 64 threads stage h -> msgh
    #pragma unroll
    for (int t = 0; t < 3; ++t) {
      const int e = idx + 64*t;            // 0..191
      const int m = e / 96, k = e - m*96;
      msgh[(96+k)*2 + m] = h[(base+m)*HD + k];
    }
  }
  __syncthreads();

  // ===== phase 3b: reduce P2 -> s3t[j][m] =====
  if (tid < 192) {
    const int m = tid / 96, j = tid - m*96;
    float v = 0.f;
    #pragma unroll
    for (int d = 0; d < 10; ++d) v += P2[j*20 + m*10 + d];
    s3t[j*2 + m] = v;
  }
  __syncthreads();

  // ===== phase 4: GEMM3  msg partials (2x96 @ 96x96, k-split 16) =====
  {
    const int j4g = tid % 24, kq = tid / 24;  // 24 x 16
    const int j4 = j4g*4, k0 = kq*6;
    const float* W3 = msg_Ws + 2*9216;
    float acc[2][4];
    #pragma unroll
    for (int m = 0; m < 2; ++m)
      #pragma unroll
      for (int jj = 0; jj < 4; ++jj) acc[m][jj] = 0.f;
    #pragma unroll
    for (int kk = 0; kk < 6; ++kk) {
      const int k = k0 + kk;
      const float2 sv = *(const float2*)&s3t[k*2];
      const float4 wv = *(const float4*)&W3[k*96 + j4];
      const float we[4] = {wv.x, wv.y, wv.z, wv.w};
      #pragma unroll
      for (int jj = 0; jj < 4; ++jj) {
        acc[0][jj] = fmaf(sv.x, we[jj], acc[0][jj]);
        acc[1][jj] = fmaf(sv.y, we[jj], acc[1][jj]);
      }
    }
    #pragma unroll
    for (int m = 0; m < 2; ++m) {
      float4 q = {acc[m][0], acc[m][1], acc[m][2], acc[m][3]};
      *(float4*)&P3[kq*192 + m*96 + j4] = q;
    }
  }
  __syncthreads();
  if (tid < 192) {
    const int m = tid / 96, j = tid - m*96;
    float v = 17.f * msg_bs[192 + j];
    #pragma unroll
    for (int kq = 0; kq < 16; ++kq) v += P3[kq*192 + m*96 + j];
    msgh[j*2 + m] = v;
  }
  __syncthreads();

  // ===== phase 5: LSTM GEMM partials ([msg|h] @ [Wih;Whh], k-split 4) =====
  {
    const int jg = tid % 96, kq = tid / 96;   // 96 x 4
    const int j4 = jg*4, k0 = kq*48;
    const float* Wp = (kq < 2) ? (W_ih + k0*384) : (W_hh + (k0-96)*384);
    float acc[2][4];
    #pragma unroll
    for (int m = 0; m < 2; ++m)
      #pragma unroll
      for (int jj = 0; jj < 4; ++jj) acc[m][jj] = 0.f;
    #pragma unroll 2
    for (int kk = 0; kk < 48; ++kk) {
      const float2 iv = *(const float2*)&msgh[(k0+kk)*2];
      const float4 wv = *(const float4*)&Wp[kk*384 + j4];
      const float we[4] = {wv.x, wv.y, wv.z, wv.w};
      #pragma unroll
      for (int jj = 0; jj < 4; ++jj) {
        acc[0][jj] = fmaf(iv.x, we[jj], acc[0][jj]);
        acc[1][jj] = fmaf(iv.y, we[jj], acc[1][jj]);
      }
    }
    #pragma unroll
    for (int m = 0; m < 2; ++m) {
      float4 q = {acc[m][0], acc[m][1], acc[m][2], acc[m][3]};
      *(float4*)&PL[kq*768 + m*384 + j4] = q;
    }
  }
  __syncthreads();
  {
    const int j = tid;
    #pragma unroll
    for (int m = 0; m < 2; ++m) {
      float g = gx[(base+m)*384 + j];
      #pragma unroll
      for (int kq = 0; kq < 4; ++kq) g += PL[kq*768 + m*384 + j];
      gates[m*384 + j] = g;
    }
  }
  __syncthreads();

  // ===== phase 6: pointwise LSTM =====
  if (tid < 192) {
    const int m = tid / 96, hj = tid - m*96;
    const int node = base + m;
    const float gi = gates[m*384 + hj];
    const float gf = gates[m*384 + 96 + hj];
    const float gg = gates[m*384 + 192 + hj];
    const float go = gates[m*384 + 288 + hj];
    const float sv = s[node*HD + hj];
    const float ig = 1.f/(1.f + expf(-gi));
    const float fg = 1.f/(1.f + expf(-gf));
    const float cg = tanhf(gg);
    const float og = 1.f/(1.f + expf(-go));
    const float s2 = fg*sv + ig*cg;
    const float h2 = og*tanhf(s2);
    s[node*HD + hj] = s2;
    h[node*HD + hj] = h2;
    h2t[hj*2 + m] = h2;
  }
  __syncthreads();

  // ===== phase 7: u_next partials (2x96 @ 96x192, k-split 8) =====
  {
    const int jg = tid % 48, kq = tid / 48;   // 48 x 8
    const int j4 = jg*4, k0 = kq*12;
    const float* Wp = (j4 < 96) ? (msg0_W + j4) : (msg0_W + 9216 + j4 - 96);
    float acc[2][4];
    #pragma unroll
    for (int m = 0; m < 2; ++m)
      #pragma unroll
      for (int jj = 0; jj < 4; ++jj) acc[m][jj] = 0.f;
    #pragma unroll 4
    for (int kk = 0; kk < 12; ++kk) {
      const int k = k0 + kk;
      const float2 iv = *(const float2*)&h2t[k*2];
      const float4 wv = *(const float4*)&Wp[k*96];
      const float we[4] = {wv.x, wv.y, wv.z, wv.w};
      #pragma unroll
      for (int jj = 0; jj < 4; ++jj) {
        acc[0][jj] = fmaf(iv.x, we[jj], acc[0][jj]);
        acc[1][jj] = fmaf(iv.y, we[jj], acc[1][jj]);
      }
    }
    #pragma unroll
    for (int m = 0; m < 2; ++m) {
      float4 q = {acc[m][0], acc[m][1], acc[m][2], acc[m][3]};
      *(float4*)&PU[kq*384 + m*192 + j4] = q;
    }
  }
  __syncthreads();

  // ===== phase 7b: reduce u_next; pred partials =====
  {
    const int j = tid % 192, m = tid / 192;
    float v = 0.f;
    #pragma unroll
    for (int kq = 0; kq < 8; ++kq) v += PU[kq*384 + m*192 + j];
    u_next[(base+m)*192 + j] = v;
  }
  if (tid < 128) {
    const int m = tid >> 6, c = (tid >> 3) & 7, kq = tid & 7;
    float p = 0.f;
    #pragma unroll
    for (int kk = 0; kk < 12; ++kk) {
      const int k = kq*12 + kk;
      p = fmaf(h2t[k*2 + m], pred_W[k*8 + c], p);
    }
    p += __shfl_xor(p, 1);
    p += __shfl_xor(p, 2);
    p += __shfl_xor(p, 4);
    if (kq == 0) lgt[m*8 + c] = p + pred_b[c];
  }
  __syncthreads();

  // ===== phase 8: softmax/argmax/loss =====
  if (tid < 2) {
    const int m = tid;
    const int node = base + m;
    float mx = lgt[m*8];
    int pred = 0;
    #pragma unroll
    for (int c = 1; c < 8; ++c) {
      const float v = lgt[m*8 + c];
      if (v > mx) { mx = v; pred = c; }
    }
    float sum = 0.f;
    #pragma unroll
    for (int c = 0; c < 8; ++c) sum += expf(lgt[m*8 + c] - mx);
    const float lse = mx + logf(sum);
    const int tgt = target[node] - 1;
    lgt[16 + m] = lse - lgt[m*8 + tgt];
    lgt[18 + m] = (pred == tgt) ? 1.f : 0.f;
    if (step == NSTEPS-1) final_pred_out[node] = (float)pred;
    if (m == 0) {
      lossP[step*NBLK + blk] = lgt[16] + lgt[17];
      cntP[step*NBLK + blk] = (int)(lgt[18] + lgt[19]);
    }
  }
}

// ---------------- finalize: accs + loss ----------------
__global__ void finalize_kernel(const float* __restrict__ lossP,
                                const int* __restrict__ cntP,
                                float* __restrict__ out)
{
  __shared__ float sl[32];
  const int tid = threadIdx.x;   // 256
  const int st = tid >> 3, q = tid & 7;
  float lsum = 0.f;
  for (int i = 0; i < 64; ++i) lsum += lossP[st*NBLK + q*64 + i];
  lsum += __shfl_xor(lsum, 1);
  lsum += __shfl_xor(lsum, 2);
  lsum += __shfl_xor(lsum, 4);
  if (q == 0) sl[st] = lsum;
  float okc = 0.f;
  #pragma unroll
  for (int t = 0; t < 2; ++t) {
    const int bbat = q + 8*t;
    int c = 0;
    for (int i = 0; i < 32; ++i) c += cntP[st*NBLK + bbat*32 + i];
    okc += (c == 64) ? 1.f : 0.f;
  }
  okc += __shfl_xor(okc, 1);
  okc += __shfl_xor(okc, 2);
  okc += __shfl_xor(okc, 4);
  if (q == 0) out[1 + st] = okc / 16.f;
  __syncthreads();
  if (tid == 0) {
    float tot = 0.f;
    for (int i = 0; i < 32; ++i) tot += sl[i];
    out[0] = tot / ((float)NODES * (float)NSTEPS);
  }
}

extern "C" void kernel_launch(void* const* d_in, const int* in_sizes, int n_in,
                              void* d_out, int out_size, void* d_ws, size_t ws_size,
                              hipStream_t stream) {
  const int*   x         = (const int*)  d_in[0];
  const int*   target    = (const int*)  d_in[1];
  const int*   edges     = (const int*)  d_in[2];
  const float* digit_emb = (const float*)d_in[3];
  const float* row_emb   = (const float*)d_in[4];
  const float* col_emb   = (const float*)d_in[5];
  const float* in0_W     = (const float*)d_in[6];
  const float* in0_b     = (const float*)d_in[7];
  const float* in_Ws     = (const float*)d_in[8];
  const float* in_bs     = (const float*)d_in[9];
  const float* msg0_W    = (const float*)d_in[10];
  const float* msg0_b    = (const float*)d_in[11];
  const float* msg_Ws    = (const float*)d_in[12];
  const float* msg_bs    = (const float*)d_in[13];
  const float* W_ih      = (const float*)d_in[14];
  const float* W_hh      = (const float*)d_in[15];
  const float* pred_W    = (const float*)d_in[18];
  const float* pred_b    = (const float*)d_in[19];

  float* ws    = (float*)d_ws;
  float* hbuf  = ws + WS_H;
  float* sbuf  = ws + WS_S;
  float* u0    = ws + WS_U0;
  float* u1    = ws + WS_U1;
  float* xin   = ws + WS_XIN;
  float* gxb   = ws + WS_GX;
  float* W1p   = ws + WS_W1P;
  float* W2p   = ws + WS_W2P;
  float* lossP = ws + WS_LOSSP;
  int*   cntP  = (int*)(ws + WS_CNTP);

  // zero h, s, u0 (everything else fully written each call)
  hipMemsetAsync(d_ws, 0, (size_t)393216*sizeof(float), stream);

  wpad_kernel<<<96, 128, 0, stream>>>(msg_Ws, W1p, W2p);
  init_kernel<<<NODES, HD, 0, stream>>>(x, digit_emb, row_emb, col_emb,
                                        in0_W, in0_b, in_Ws, in_bs, xin);
  gx_kernel<<<256, 384, 0, stream>>>(xin, W_ih,
                                     (const float*)d_in[16], (const float*)d_in[17],
                                     gxb);

  float* outp = (float*)d_out;
  for (int st = 0; st < NSTEPS; ++st) {
    const float* up = (st & 1) ? u1 : u0;
    float*       un = (st & 1) ? u0 : u1;
    step_kernel<<<NBLK, 384, 0, stream>>>(
        up, un, hbuf, sbuf, gxb, edges,
        W1p, W2p, msg0_W, msg0_b, msg_Ws, msg_bs,
        W_ih, W_hh, pred_W, pred_b,
        target, lossP, cntP, outp + 1 + NSTEPS, st);
  }

  finalize_kernel<<<1, 256, 0, stream>>>(lossP, cntP, outp);
}